// Round 2
// baseline (58.753 us; speedup 1.0000x reference)
//
#include <hip/hip_runtime.h>

// Problem constants (match reference)
#define NG   48
#define NG2  (NG * NG)
#define NG3  (NG * NG * NG)
#define N_ATOMS 1024

// Single fused kernel: each block owns an 8x8x8 voxel tile (grid 6x6x6).
// Phase 1: compact the atoms that can possibly cover this tile into LDS
//          (conservative bounding-box test, margin > r).
// Phase 2: each thread (1 voxel) does the exact fp32 coverage test against
//          the candidate list and writes BOTH channels' final values.
// No init kernel needed: every voxel is written exactly once.
__global__ __launch_bounds__(512) void wat_fused(const float* __restrict__ vecs,
                                                 float* __restrict__ out) {
    __shared__ float cx[N_ATOMS], cy[N_ATOMS], cz[N_ATOMS];
    __shared__ int ncand;

    const int t = threadIdx.x;
    if (t == 0) ncand = 0;
    __syncthreads();

    const int bx0 = blockIdx.x * 8;
    const int by0 = blockIdx.y * 8;
    const int bz0 = blockIdx.z * 8;

    // r = 1.5*1.52 = 2.28; margin slightly larger to absorb fp32 rounding
    const float margin = 2.2805f;
    const float lox = 0.5f * (float)bx0 - margin;
    const float hix = 0.5f * (float)(bx0 + 7) + margin;
    const float loy = 0.5f * (float)by0 - margin;
    const float hiy = 0.5f * (float)(by0 + 7) + margin;
    const float loz = 0.5f * (float)bz0 - margin;
    const float hiz = 0.5f * (float)(bz0 + 7) + margin;

    // Phase 1: candidate compaction (expected ~46 of 1024 atoms)
    for (int a = t; a < N_ATOMS; a += 512) {
        const float ax = vecs[3 * a + 0];
        const float ay = vecs[3 * a + 1];
        const float az = vecs[3 * a + 2];
        if (ax >= lox && ax <= hix &&
            ay >= loy && ay <= hiy &&
            az >= loz && az <= hiz) {
            const int p = atomicAdd(&ncand, 1);
            cx[p] = ax; cy[p] = ay; cz[p] = az;
        }
    }
    __syncthreads();
    const int n = ncand;

    // Phase 2: exact test, one voxel per thread
    const int lz = t & 7;
    const int ly = (t >> 3) & 7;
    const int lx = t >> 6;
    const int ix = bx0 + lx;
    const int iy = by0 + ly;
    const int iz = bz0 + lz;
    const float vx = 0.5f * (float)ix;   // exact in fp32
    const float vy = 0.5f * (float)iy;
    const float vz = 0.5f * (float)iz;

    // r^2 exactly as the reference computes it: double (1.5*1.52)^2 -> fp32
    const double rd = 1.5 * 1.52;
    const float R2 = (float)(rd * rd);

    bool covered = false;
    for (int i = 0; i < n; ++i) {
        // Bit-exact reference fp32 arithmetic: d2 = (dx^2 + dy^2) + dz^2
        const float dx = __fsub_rn(cx[i], vx);
        const float dy = __fsub_rn(cy[i], vy);
        const float dz = __fsub_rn(cz[i], vz);
        const float d2 = __fadd_rn(__fadd_rn(__fmul_rn(dx, dx),
                                             __fmul_rn(dy, dy)),
                                   __fmul_rn(dz, dz));
        if (d2 < R2) { covered = true; break; }
    }

    const int idx = ix * NG2 + iy * NG + iz;
    out[idx]       = covered ? 1.0f  : 0.0f;   // ch0
    out[NG3 + idx] = covered ? 25.0f : 1.0f;   // ch1
}

extern "C" void kernel_launch(void* const* d_in, const int* in_sizes, int n_in,
                              void* d_out, int out_size, void* d_ws, size_t ws_size,
                              hipStream_t stream) {
    const float* vecs = (const float*)d_in[0];
    float* out = (float*)d_out;

    dim3 grid(NG / 8, NG / 8, NG / 8);   // 6x6x6 = 216 blocks
    wat_fused<<<grid, 512, 0, stream>>>(vecs, out);
}

// Round 3
// 54.410 us; speedup vs baseline: 1.0798x; 1.0798x over previous
//
#include <hip/hip_runtime.h>

// Problem constants (match reference)
#define NG   48
#define NG2  (NG * NG)
#define NG3  (NG * NG * NG)
#define N_ATOMS 1024

// Single fused kernel: each block owns an 8x8x8 voxel tile (grid 6x6x6).
// Phase 1: compact atoms that can cover this tile into LDS (float4-packed).
// Phase 2: branchless OR-reduction over candidates (no early exit -> compiler
//          unrolls and pipelines ds_read_b128 at throughput instead of
//          paying ~120cyc latency per iteration on a dependent break chain).
__global__ __launch_bounds__(512) void wat_fused(const float* __restrict__ vecs,
                                                 float* __restrict__ out) {
    __shared__ float4 cand[N_ATOMS];
    __shared__ int ncand;

    const int t = threadIdx.x;
    if (t == 0) ncand = 0;
    __syncthreads();

    const int bx0 = blockIdx.x * 8;
    const int by0 = blockIdx.y * 8;
    const int bz0 = blockIdx.z * 8;

    // r = 1.5*1.52 = 2.28; margin slightly larger to absorb fp32 rounding
    const float margin = 2.2805f;
    const float lox = 0.5f * (float)bx0 - margin;
    const float hix = 0.5f * (float)(bx0 + 7) + margin;
    const float loy = 0.5f * (float)by0 - margin;
    const float hiy = 0.5f * (float)(by0 + 7) + margin;
    const float loz = 0.5f * (float)bz0 - margin;
    const float hiz = 0.5f * (float)(bz0 + 7) + margin;

    // Phase 1: candidate compaction (expected ~46 of 1024 atoms)
    for (int a = t; a < N_ATOMS; a += 512) {
        const float ax = vecs[3 * a + 0];
        const float ay = vecs[3 * a + 1];
        const float az = vecs[3 * a + 2];
        if (ax >= lox && ax <= hix &&
            ay >= loy && ay <= hiy &&
            az >= loz && az <= hiz) {
            const int p = atomicAdd(&ncand, 1);
            cand[p] = make_float4(ax, ay, az, 0.0f);
        }
    }
    __syncthreads();
    const int n = ncand;

    // Phase 2: exact test, one voxel per thread, branchless accumulate
    const int lz = t & 7;
    const int ly = (t >> 3) & 7;
    const int lx = t >> 6;
    const int ix = bx0 + lx;
    const int iy = by0 + ly;
    const int iz = bz0 + lz;
    const float vx = 0.5f * (float)ix;   // exact in fp32
    const float vy = 0.5f * (float)iy;
    const float vz = 0.5f * (float)iz;

    // r^2 exactly as the reference computes it: double (1.5*1.52)^2 -> fp32
    const double rd = 1.5 * 1.52;
    const float R2 = (float)(rd * rd);

    bool covered = false;
    #pragma unroll 4
    for (int i = 0; i < n; ++i) {
        const float4 c = cand[i];
        // Bit-exact reference fp32 arithmetic: d2 = (dx^2 + dy^2) + dz^2
        const float dx = __fsub_rn(c.x, vx);
        const float dy = __fsub_rn(c.y, vy);
        const float dz = __fsub_rn(c.z, vz);
        const float d2 = __fadd_rn(__fadd_rn(__fmul_rn(dx, dx),
                                             __fmul_rn(dy, dy)),
                                   __fmul_rn(dz, dz));
        covered |= (d2 < R2);
    }

    const int idx = ix * NG2 + iy * NG + iz;
    out[idx]       = covered ? 1.0f  : 0.0f;   // ch0
    out[NG3 + idx] = covered ? 25.0f : 1.0f;   // ch1
}

extern "C" void kernel_launch(void* const* d_in, const int* in_sizes, int n_in,
                              void* d_out, int out_size, void* d_ws, size_t ws_size,
                              hipStream_t stream) {
    const float* vecs = (const float*)d_in[0];
    float* out = (float*)d_out;

    dim3 grid(NG / 8, NG / 8, NG / 8);   // 6x6x6 = 216 blocks
    wat_fused<<<grid, 512, 0, stream>>>(vecs, out);
}